// Round 2
// baseline (3511.258 us; speedup 1.0000x reference)
//
#include <hip/hip_runtime.h>

// ---------------------------------------------------------------------------
// BiSSM global block, MI355X.
// Structure:
//   k_abuild : A = diag(-(i+1)/H) + U V^T + (S - S^T); store A f32 (rm + tr),
//              A bf16 rm, diag residual; convert Bm/Cm/gw to bf16.
//   k_rms    : RMSNorm -> xn bf16, stored in (t,b) row order.
//   k_gemm_u : u[t,b,h] = xn @ Bm^T  (bf16 MFMA, bf16 out)
//   k_sq x7  : squaring chain A->A^2->...->A^128 (hi/lo bf16, f32 storage);
//              emit bf16+diag-residual at A^16 and A^128.
//   k_scan x5: chunked linear scans (fwd+bwd stacked as M=16 rows/block):
//              l1p1 (local, L=16, 128 blocks) -> edges
//              l2p1 (local over edges, L=8, 16 blocks) -> group edges
//              l3   (over group edges, L=16, 1 block)  -> group inits
//              l2p3 (rerun w/ init) -> chunk boundary states
//              l1p3 (rerun w/ init) -> hf/hb bf16 per-timestep states
//   k_final  : out = x + alpha*0.5*((hf+hb)@Cm^T) * sigmoid(xn@gw^T + gb)
// Precision: matrices applied repeatedly are bf16 + f32 diagonal-residual
// correction (diagonal dominates eigenvalue drift); power chain uses hi/lo
// bf16 (3 MFMA passes) so squaring errors don't compound.
// ---------------------------------------------------------------------------

typedef short  bfrag __attribute__((ext_vector_type(8)));   // 8 x bf16
typedef float  ffrag __attribute__((ext_vector_type(4)));   // mfma acc
typedef float  f4    __attribute__((ext_vector_type(4)));

#define DEV static __device__ __forceinline__

DEV unsigned short f2bf(float f) {
  unsigned u = __float_as_uint(f);
  u += 0x7fffu + ((u >> 16) & 1u);            // round-to-nearest-even
  return (unsigned short)(u >> 16);
}
DEV float bf2f(unsigned short s) { return __uint_as_float(((unsigned)s) << 16); }

DEV ffrag mfma16(bfrag a, bfrag b, ffrag c) {
  return __builtin_amdgcn_mfma_f32_16x16x32_bf16(a, b, c, 0, 0, 0);
}

union BF8 { bfrag v; unsigned short u[8]; };

#define Hn 768
#define Nn 2048
#define Bb 8

// ---------------------------------------------------------------------------
// k_abuild: gridDim = (768, 4); task = blockIdx.y
//   0: build A row i ; 1/2/3: convert Bm/Cm/gw row i to bf16
__global__ __launch_bounds__(256) void k_abuild(
    const float* __restrict__ U, const float* __restrict__ V,
    const float* __restrict__ S, const float* __restrict__ Bm,
    const float* __restrict__ Cm, const float* __restrict__ gw,
    float* __restrict__ Af, float* __restrict__ AfT,
    unsigned short* __restrict__ Abf, float* __restrict__ dresA,
    unsigned short* __restrict__ Bmb, unsigned short* __restrict__ Cmb,
    unsigned short* __restrict__ gwb) {
  int i = blockIdx.x;
  int task = blockIdx.y;
  if (task == 0) {
    float u0 = U[i*4+0], u1 = U[i*4+1], u2 = U[i*4+2], u3 = U[i*4+3];
    for (int j = threadIdx.x; j < Hn; j += 256) {
      float a = u0*V[j*4+0] + u1*V[j*4+1] + u2*V[j*4+2] + u3*V[j*4+3]
              + S[i*Hn+j] - S[j*Hn+i];
      if (i == j) a += -(float)(i+1) / 768.0f;
      Af[i*Hn+j]  = a;
      AfT[j*Hn+i] = a;
      unsigned short ab = f2bf(a);
      Abf[i*Hn+j] = ab;
      if (i == j) dresA[i] = a - bf2f(ab);
    }
  } else {
    const float* src = (task==1) ? Bm : (task==2) ? Cm : gw;
    unsigned short* dst = (task==1) ? Bmb : (task==2) ? Cmb : gwb;
    for (int j = threadIdx.x; j < Hn; j += 256) dst[i*Hn+j] = f2bf(src[i*Hn+j]);
  }
}

// ---------------------------------------------------------------------------
// k_rms: one wave per row (row = b*2048 + t); write xn in (t,b) order, bf16.
__global__ __launch_bounds__(256) void k_rms(
    const float* __restrict__ x, const float* __restrict__ scale,
    unsigned short* __restrict__ xn) {
  int row  = blockIdx.x * 4 + (threadIdx.x >> 6);
  int lane = threadIdx.x & 63;
  int b = row >> 11, t = row & 2047;
  const float* xr = x + (long)row * Hn;
  float v[12];
  float ss = 0.f;
#pragma unroll
  for (int j = 0; j < 12; ++j) { v[j] = xr[lane + j*64]; ss += v[j]*v[j]; }
#pragma unroll
  for (int off = 1; off < 64; off <<= 1) ss += __shfl_xor(ss, off);
  float inv = 1.0f / sqrtf(ss / 768.0f + 1e-8f);
  unsigned short* dst = xn + ((long)t * Bb + b) * Hn;
#pragma unroll
  for (int j = 0; j < 12; ++j) dst[lane + j*64] = f2bf(v[j] * inv * scale[lane + j*64]);
}

// ---------------------------------------------------------------------------
// k_gemm_u: u = xn @ Bm^T.  grid (256, 6), 512 thr. tile 64 rows x 128 cols.
__global__ __launch_bounds__(512) void k_gemm_u(
    const unsigned short* __restrict__ xn, const unsigned short* __restrict__ Bmb,
    unsigned short* __restrict__ u) {
  int tid = threadIdx.x, lane = tid & 63, w = tid >> 6;
  int mw = w >> 2, nw = w & 3, l15 = lane & 15, lhi = lane >> 4;
  long rb = (long)blockIdx.x * 64;
  int  cb = blockIdx.y * 128;
  ffrag acc[2][2] = {};
  for (int kt = 0; kt < 24; ++kt) {
    int k0 = kt*32 + lhi*8;
    bfrag a[2], b[2];
#pragma unroll
    for (int mt = 0; mt < 2; ++mt)
      a[mt] = *(const bfrag*)(xn + (rb + mw*32 + mt*16 + l15) * Hn + k0);
#pragma unroll
    for (int nt = 0; nt < 2; ++nt)
      b[nt] = *(const bfrag*)(Bmb + (long)(cb + nw*32 + nt*16 + l15) * Hn + k0);
#pragma unroll
    for (int mt = 0; mt < 2; ++mt)
#pragma unroll
      for (int nt = 0; nt < 2; ++nt)
        acc[mt][nt] = mfma16(a[mt], b[nt], acc[mt][nt]);
  }
#pragma unroll
  for (int mt = 0; mt < 2; ++mt)
#pragma unroll
    for (int nt = 0; nt < 2; ++nt)
#pragma unroll
      for (int q = 0; q < 4; ++q) {
        long grow = rb + mw*32 + mt*16 + lhi*4 + q;
        int  gcol = cb + nw*32 + nt*16 + l15;
        u[grow * Hn + gcol] = f2bf(acc[mt][nt][q]);
      }
}

// ---------------------------------------------------------------------------
// k_sq: Z = X @ X with hi/lo bf16 (3 passes). X given row-major and transposed.
// Writes Z row-major + Z^T row-major (f32); optional bf16 + diag residual.
// grid (12, 6), 512 thr, tile 64x128.
__global__ __launch_bounds__(512) void k_sq(
    const float* __restrict__ X, const float* __restrict__ XT,
    float* __restrict__ Z, float* __restrict__ ZT,
    unsigned short* __restrict__ Zbf, float* __restrict__ dresZ) {
  int tid = threadIdx.x, lane = tid & 63, w = tid >> 6;
  int mw = w >> 2, nw = w & 3, l15 = lane & 15, lhi = lane >> 4;
  int rb = blockIdx.x * 64, cb = blockIdx.y * 128;
  ffrag acc[2][2] = {};
  for (int kt = 0; kt < 24; ++kt) {
    int k0 = kt*32 + lhi*8;
    BF8 ah[2], al[2], bh[2], bl[2];
#pragma unroll
    for (int mt = 0; mt < 2; ++mt) {
      const f4* p = (const f4*)(X + (long)(rb + mw*32 + mt*16 + l15) * Hn + k0);
      f4 x0 = p[0], x1 = p[1];
#pragma unroll
      for (int j = 0; j < 8; ++j) {
        float f = (j < 4) ? x0[j] : x1[j-4];
        unsigned short h = f2bf(f);
        ah[mt].u[j] = h; al[mt].u[j] = f2bf(f - bf2f(h));
      }
    }
#pragma unroll
    for (int nt = 0; nt < 2; ++nt) {
      const f4* p = (const f4*)(XT + (long)(cb + nw*32 + nt*16 + l15) * Hn + k0);
      f4 x0 = p[0], x1 = p[1];
#pragma unroll
      for (int j = 0; j < 8; ++j) {
        float f = (j < 4) ? x0[j] : x1[j-4];
        unsigned short h = f2bf(f);
        bh[nt].u[j] = h; bl[nt].u[j] = f2bf(f - bf2f(h));
      }
    }
#pragma unroll
    for (int mt = 0; mt < 2; ++mt)
#pragma unroll
      for (int nt = 0; nt < 2; ++nt) {
        acc[mt][nt] = mfma16(ah[mt].v, bh[nt].v, acc[mt][nt]);
        acc[mt][nt] = mfma16(ah[mt].v, bl[nt].v, acc[mt][nt]);
        acc[mt][nt] = mfma16(al[mt].v, bh[nt].v, acc[mt][nt]);
      }
  }
#pragma unroll
  for (int mt = 0; mt < 2; ++mt)
#pragma unroll
    for (int nt = 0; nt < 2; ++nt)
#pragma unroll
      for (int q = 0; q < 4; ++q) {
        int grow = rb + mw*32 + mt*16 + lhi*4 + q;
        int gcol = cb + nw*32 + nt*16 + l15;
        float vv = acc[mt][nt][q];
        Z[(long)grow*Hn + gcol] = vv;
        ZT[(long)gcol*Hn + grow] = vv;
        if (Zbf) Zbf[(long)grow*Hn + gcol] = f2bf(vv);
        if (dresZ && grow == gcol) dresZ[gcol] = vv - bf2f(f2bf(vv));
      }
}

// ---------------------------------------------------------------------------
// k_scan: generic chunked scan step kernel.
// Block = 256 thr (4 waves); M = 16 rows: rows 0-7 fwd chain, 8-15 bwd chain.
// Per step s: acc = in[idx] ; acc += h @ Mat(bf16) ; acc += h .* dres ;
//             h <- acc ; optional per-step / edge outputs.
// fwd input idx = bid*steps + s ; bwd input idx = bid*steps + (steps-1-s).
// init (rerun mode): fwd from initf[bid-1], bwd from initb[bid+1].
__global__ __launch_bounds__(256) void k_scan(
    const unsigned short* __restrict__ mat, const float* __restrict__ dres,
    const void* __restrict__ inf, const void* __restrict__ inb, int in_bf16,
    const float* __restrict__ initf, const float* __restrict__ initb,
    float* __restrict__ outf_f, float* __restrict__ outf_b,
    unsigned short* __restrict__ outbf_f, unsigned short* __restrict__ outbf_b,
    float* __restrict__ edgef, float* __restrict__ edgeb,
    int steps) {
  __shared__ unsigned short hbuf[16][776];
  const int tid = threadIdx.x, lane = tid & 63, w = tid >> 6;
  const int bid = blockIdx.x;
  const int l15 = lane & 15, lhi = lane >> 4;

  // init h
  for (int i = tid; i < 16 * Hn; i += 256) {
    int r = i / Hn, c = i % Hn;
    float v = 0.f;
    if (r < 8) { if (initf && bid > 0) v = initf[((long)(bid-1)*8 + r)*Hn + c]; }
    else       { if (initb && bid + 1 < (int)gridDim.x) v = initb[((long)(bid+1)*8 + (r-8))*Hn + c]; }
    hbuf[r][c] = f2bf(v);
  }
  __syncthreads();

  ffrag acc[12];
  for (int s = 0; s < steps; ++s) {
    const long idxf = (long)bid * steps + s;
    const long idxb = (long)bid * steps + (steps - 1 - s);
    // acc <- input
#pragma unroll
    for (int t = 0; t < 12; ++t) {
      int col = (w*12 + t)*16 + l15;
#pragma unroll
      for (int q = 0; q < 4; ++q) {
        int row = lhi*4 + q;
        long off = (row < 8) ? (idxf*8 + row)*Hn + col
                             : (idxb*8 + (row-8))*Hn + col;
        const void* src = (row < 8) ? inf : inb;
        acc[t][q] = in_bf16 ? bf2f(((const unsigned short*)src)[off])
                            : ((const float*)src)[off];
      }
    }
    // acc += h @ Mat
    for (int kt = 0; kt < 24; ++kt) {
      int k0 = kt*32 + lhi*8;
      bfrag ha = *(const bfrag*)&hbuf[l15][k0];
#pragma unroll
      for (int t = 0; t < 12; ++t) {
        int n = (w*12 + t)*16 + l15;
        bfrag bb = *(const bfrag*)(mat + (long)n * Hn + k0);
        acc[t] = mfma16(ha, bb, acc[t]);
      }
    }
    // diagonal residual correction (uses OLD h)
#pragma unroll
    for (int t = 0; t < 12; ++t) {
      int col = (w*12 + t)*16 + l15;
      float dv = dres[col];
#pragma unroll
      for (int q = 0; q < 4; ++q) {
        int row = lhi*4 + q;
        acc[t][q] += bf2f(hbuf[row][col]) * dv;
      }
    }
    __syncthreads();   // all reads of old h done
    // h <- acc ; outputs
#pragma unroll
    for (int t = 0; t < 12; ++t) {
      int col = (w*12 + t)*16 + l15;
#pragma unroll
      for (int q = 0; q < 4; ++q) {
        int row = lhi*4 + q;
        float v = acc[t][q];
        hbuf[row][col] = f2bf(v);
        if (row < 8) {
          long off = (idxf*8 + row)*Hn + col;
          if (outf_f)  outf_f[off]  = v;
          if (outbf_f) outbf_f[off] = f2bf(v);
        } else {
          long off = (idxb*8 + (row-8))*Hn + col;
          if (outf_b)  outf_b[off]  = v;
          if (outbf_b) outbf_b[off] = f2bf(v);
        }
      }
    }
    __syncthreads();
  }
  if (edgef) {
#pragma unroll
    for (int t = 0; t < 12; ++t) {
      int col = (w*12 + t)*16 + l15;
#pragma unroll
      for (int q = 0; q < 4; ++q) {
        int row = lhi*4 + q;
        if (row < 8) edgef[((long)bid*8 + row)*Hn + col] = acc[t][q];
        else         edgeb[((long)bid*8 + (row-8))*Hn + col] = acc[t][q];
      }
    }
  }
}

// ---------------------------------------------------------------------------
// k_final: out = x + alpha * 0.5*((hf+hb)@Cm^T) * sigmoid(xn@gw^T + gb)
// grid (256, 6), 512 thr, tile 64 rows x 128 cols. rows are (t*8+b).
__global__ __launch_bounds__(512) void k_final(
    const unsigned short* __restrict__ xn, const unsigned short* __restrict__ hf,
    const unsigned short* __restrict__ hb,
    const unsigned short* __restrict__ Cmb, const unsigned short* __restrict__ gwb,
    const float* __restrict__ gate_b, const float* __restrict__ alpha,
    const float* __restrict__ x, float* __restrict__ out) {
  int tid = threadIdx.x, lane = tid & 63, w = tid >> 6;
  int mw = w >> 2, nw = w & 3, l15 = lane & 15, lhi = lane >> 4;
  long rb = (long)blockIdx.x * 64;
  int  cb = blockIdx.y * 128;
  ffrag ay[2][2] = {}, az[2][2] = {};
  for (int kt = 0; kt < 24; ++kt) {
    int k0 = kt*32 + lhi*8;
    bfrag axv[2], afv[2], abv[2], bcv[2], bgv[2];
#pragma unroll
    for (int mt = 0; mt < 2; ++mt) {
      long r = (rb + mw*32 + mt*16 + l15) * Hn + k0;
      axv[mt] = *(const bfrag*)(xn + r);
      afv[mt] = *(const bfrag*)(hf + r);
      abv[mt] = *(const bfrag*)(hb + r);
    }
#pragma unroll
    for (int nt = 0; nt < 2; ++nt) {
      long c = (long)(cb + nw*32 + nt*16 + l15) * Hn + k0;
      bcv[nt] = *(const bfrag*)(Cmb + c);
      bgv[nt] = *(const bfrag*)(gwb + c);
    }
#pragma unroll
    for (int mt = 0; mt < 2; ++mt)
#pragma unroll
      for (int nt = 0; nt < 2; ++nt) {
        ay[mt][nt] = mfma16(afv[mt], bcv[nt], ay[mt][nt]);
        ay[mt][nt] = mfma16(abv[mt], bcv[nt], ay[mt][nt]);
        az[mt][nt] = mfma16(axv[mt], bgv[nt], az[mt][nt]);
      }
  }
  float al = alpha[0];
#pragma unroll
  for (int mt = 0; mt < 2; ++mt)
#pragma unroll
    for (int nt = 0; nt < 2; ++nt)
#pragma unroll
      for (int q = 0; q < 4; ++q) {
        long grow = rb + mw*32 + mt*16 + lhi*4 + q;
        int  gcol = cb + nw*32 + nt*16 + l15;
        long t = grow >> 3, b = grow & 7;
        long o = (b * Nn + t) * Hn + gcol;
        float z = az[mt][nt][q] + gate_b[gcol];
        float g = 1.0f / (1.0f + __expf(-z));
        out[o] = x[o] + al * 0.5f * ay[mt][nt][q] * g;
      }
}

// ---------------------------------------------------------------------------
extern "C" void kernel_launch(void* const* d_in, const int* in_sizes, int n_in,
                              void* d_out, int out_size, void* d_ws, size_t ws_size,
                              hipStream_t stream) {
  const float* x     = (const float*)d_in[0];
  const float* scale = (const float*)d_in[1];
  const float* U     = (const float*)d_in[2];
  const float* V     = (const float*)d_in[3];
  const float* S     = (const float*)d_in[4];
  const float* Bm    = (const float*)d_in[5];
  const float* Cm    = (const float*)d_in[6];
  const float* gw    = (const float*)d_in[7];
  const float* gb    = (const float*)d_in[8];
  const float* alpha = (const float*)d_in[9];
  float* out = (float*)d_out;

  char* p = (char*)d_ws;
  auto alloc = [&](size_t sz) { char* r = p; p += (sz + 255) & ~(size_t)255; return r; };

  const size_t SZ_BF = (size_t)Nn * Bb * Hn * sizeof(unsigned short); // 25.2MB
  const size_t SZ_M  = (size_t)Hn * Hn * sizeof(float);               // 2.36MB
  const size_t SZ_MB = (size_t)Hn * Hn * sizeof(unsigned short);      // 1.18MB

  unsigned short* xn  = (unsigned short*)alloc(SZ_BF);
  unsigned short* u   = (unsigned short*)alloc(SZ_BF);
  unsigned short* hfb = (unsigned short*)alloc(SZ_BF);
  unsigned short* hbb = (unsigned short*)alloc(SZ_BF);
  float* Af   = (float*)alloc(SZ_M);
  float* AfT  = (float*)alloc(SZ_M);
  float* P1   = (float*)alloc(SZ_M);
  float* P1T  = (float*)alloc(SZ_M);
  float* P2   = (float*)alloc(SZ_M);
  float* P2T  = (float*)alloc(SZ_M);
  unsigned short* Abf    = (unsigned short*)alloc(SZ_MB);
  unsigned short* A16bf  = (unsigned short*)alloc(SZ_MB);
  unsigned short* A128bf = (unsigned short*)alloc(SZ_MB);
  unsigned short* Bmb    = (unsigned short*)alloc(SZ_MB);
  unsigned short* Cmb    = (unsigned short*)alloc(SZ_MB);
  unsigned short* gwb    = (unsigned short*)alloc(SZ_MB);
  float* dresA   = (float*)alloc(Hn * sizeof(float));
  float* dres16  = (float*)alloc(Hn * sizeof(float));
  float* dres128 = (float*)alloc(Hn * sizeof(float));
  float* Ef = (float*)alloc((size_t)128 * 8 * Hn * sizeof(float));
  float* Eb = (float*)alloc((size_t)128 * 8 * Hn * sizeof(float));
  float* Ff = (float*)alloc((size_t)16 * 8 * Hn * sizeof(float));
  float* Fb = (float*)alloc((size_t)16 * 8 * Hn * sizeof(float));
  float* Gf = (float*)alloc((size_t)16 * 8 * Hn * sizeof(float));
  float* Gb = (float*)alloc((size_t)16 * 8 * Hn * sizeof(float));
  float* Hf = (float*)alloc((size_t)128 * 8 * Hn * sizeof(float));
  float* Hb = (float*)alloc((size_t)128 * 8 * Hn * sizeof(float));

  if ((size_t)(p - (char*)d_ws) > ws_size) return;  // workspace too small

  // prep
  k_abuild<<<dim3(768, 4), 256, 0, stream>>>(U, V, S, Bm, Cm, gw,
      Af, AfT, Abf, dresA, Bmb, Cmb, gwb);

  k_rms<<<4096, 256, 0, stream>>>(x, scale, xn);
  k_gemm_u<<<dim3(256, 6), 512, 0, stream>>>(xn, Bmb, u);

  // squaring chain: A->A2->A4->A8->A16(emit)->A32->A64->A128(emit)
  k_sq<<<dim3(12, 6), 512, 0, stream>>>(Af,  AfT, P1, P1T, nullptr, nullptr);
  k_sq<<<dim3(12, 6), 512, 0, stream>>>(P1, P1T, P2, P2T, nullptr, nullptr);
  k_sq<<<dim3(12, 6), 512, 0, stream>>>(P2, P2T, P1, P1T, nullptr, nullptr);
  k_sq<<<dim3(12, 6), 512, 0, stream>>>(P1, P1T, P2, P2T, A16bf, dres16);
  k_sq<<<dim3(12, 6), 512, 0, stream>>>(P2, P2T, P1, P1T, nullptr, nullptr);
  k_sq<<<dim3(12, 6), 512, 0, stream>>>(P1, P1T, P2, P2T, nullptr, nullptr);
  k_sq<<<dim3(12, 6), 512, 0, stream>>>(P2, P2T, P1, P1T, A128bf, dres128);

  // scans
  k_scan<<<128, 256, 0, stream>>>(Abf, dresA, u, u, 1,
      nullptr, nullptr, nullptr, nullptr, nullptr, nullptr, Ef, Eb, 16);
  k_scan<<<16, 256, 0, stream>>>(A16bf, dres16, Ef, Eb, 0,
      nullptr, nullptr, nullptr, nullptr, nullptr, nullptr, Ff, Fb, 8);
  k_scan<<<1, 256, 0, stream>>>(A128bf, dres128, Ff, Fb, 0,
      nullptr, nullptr, Gf, Gb, nullptr, nullptr, nullptr, nullptr, 16);
  k_scan<<<16, 256, 0, stream>>>(A16bf, dres16, Ef, Eb, 0,
      Gf, Gb, Hf, Hb, nullptr, nullptr, nullptr, nullptr, 8);
  k_scan<<<128, 256, 0, stream>>>(Abf, dresA, u, u, 1,
      Hf, Hb, nullptr, nullptr, hfb, hbb, nullptr, nullptr, 16);

  k_final<<<dim3(256, 6), 512, 0, stream>>>(xn, hfb, hbb, Cmb, gwb, gb, alpha, x, out);
}